// Round 4
// baseline (1386.508 us; speedup 1.0000x reference)
//
#include <hip/hip_runtime.h>

// ---------------- problem constants (fixed by setup_inputs) ----------------
#define T_TOK 2048
#define NEXP  8
#define H_DIM 1024
#define I_DIM 4096

#define KP13 (H_DIM/8)     // 128 packed rows, W13
#define N13  (2*I_DIM)     // 8192 cols, W13
#define KP2  (I_DIM/8)     // 512 packed rows, W2
#define N2   (H_DIM)       // 1024 cols, W2
#define NG13 8             // H/128 groups
#define NG2  32            // I/128 groups

// ---------------- tiles ----------------
#define BM 128
#define BN 64
#define BK 32
#define MT1 (T_TOK/BM)     // 16 worst-case m-tiles per expert
#define NT1 (H_DIM/BK)     // 32 k-iters, gemm1
#define KSPLIT2 2
#define KLEN2 (I_DIM/KSPLIT2)   // 2048
#define NT2 (KLEN2/BK)          // 64 k-iters, gemm2

typedef __bf16 bf16x8 __attribute__((ext_vector_type(8)));
typedef float  f32x4  __attribute__((ext_vector_type(4)));
typedef int    i32x4  __attribute__((ext_vector_type(4)));

// ---------------- workspace layout (bytes) ----------------
#define WS_COUNTS 0
#define WS_OFFS   64
#define WS_CURS   128
#define WS_TOKE   256
#define WS_TOKW   (WS_TOKE  + 2*T_TOK*4)
#define WS_PLIST  (WS_TOKW  + 2*T_TOK*4)
#define WS_PW     (WS_PLIST + 2*T_TOK*4)
#define PAIR_PAD  (2*T_TOK + 128)                 // 128 rows slack for tile overread
#define WS_XG     131072
#define WS_ACT    (WS_XG + PAIR_PAD*H_DIM*2)      // bf16 act[pairs][I_DIM]

// =====================================================================
// Routing
// =====================================================================
__global__ void k_route(const float* __restrict__ logits,
                        int* __restrict__ counts,
                        int* __restrict__ tok_e, float* __restrict__ tok_w) {
    int t = blockIdx.x * blockDim.x + threadIdx.x;
    if (t >= T_TOK) return;
    float l[NEXP];
    #pragma unroll
    for (int e = 0; e < NEXP; e++) l[e] = logits[t * NEXP + e];
    int i0 = 0; float b0 = l[0];
    #pragma unroll
    for (int e = 1; e < NEXP; e++) if (l[e] > b0) { b0 = l[e]; i0 = e; }
    int i1 = -1; float b1 = -1e30f;
    #pragma unroll
    for (int e = 0; e < NEXP; e++) if (e != i0 && l[e] > b1) { b1 = l[e]; i1 = e; }
    float w1 = 1.f / (1.f + __expf(b0 - b1));
    float w0 = 1.f - w1;
    tok_e[2*t] = i0; tok_e[2*t+1] = i1;
    tok_w[2*t] = w0; tok_w[2*t+1] = w1;
    atomicAdd(&counts[i0], 1);
    atomicAdd(&counts[i1], 1);
}

__global__ void k_scan(const int* __restrict__ counts,
                       int* __restrict__ offs, int* __restrict__ curs) {
    if (threadIdx.x == 0) {
        int s = 0;
        for (int e = 0; e < NEXP; e++) { offs[e] = s; curs[e] = s; s += counts[e]; }
        offs[NEXP] = s;
    }
}

__global__ void k_scatter(const int* __restrict__ tok_e, const float* __restrict__ tok_w,
                          int* __restrict__ curs,
                          int* __restrict__ plist, float* __restrict__ pw) {
    int t = blockIdx.x * blockDim.x + threadIdx.x;
    if (t >= T_TOK) return;
    #pragma unroll
    for (int s = 0; s < 2; s++) {
        int e = tok_e[2*t+s];
        int pos = atomicAdd(&curs[e], 1);
        plist[pos] = t;
        pw[pos] = tok_w[2*t+s];
    }
}

// gather x rows in pair order, fp32 -> bf16
__global__ void k_gather(const float* __restrict__ x, const int* __restrict__ plist,
                         __bf16* __restrict__ xg) {
    int p = blockIdx.x;
    int t = plist[p];
    int i = threadIdx.x;                       // 0..127, 8 elems each
    const f32x4* src = reinterpret_cast<const f32x4*>(x + (size_t)t * H_DIM);
    f32x4 v0 = src[i*2], v1 = src[i*2+1];
    __align__(16) __bf16 tb[8];
    #pragma unroll
    for (int j = 0; j < 4; j++) { tb[j] = (__bf16)v0[j]; tb[4+j] = (__bf16)v1[j]; }
    *reinterpret_cast<f32x4*>(xg + (size_t)p * H_DIM + i*8) = *reinterpret_cast<f32x4*>(tb);
}

// =====================================================================
// GEMM1: act[p,n] = w_p * silu(xg@Wg) * (xg@Wu)
// Barrier-free: A-frags direct from global, B dequantized in-register.
// =====================================================================
__global__ __launch_bounds__(256) void k_gemm1(
    const __bf16* __restrict__ xg,
    const int*    __restrict__ w13q,
    const float*  __restrict__ w13s,
    const int*    __restrict__ g13,
    const int*    __restrict__ offs,
    const float*  __restrict__ pw,
    __bf16*       __restrict__ act) {

    const int e  = blockIdx.x / MT1;
    const int mt = blockIdx.x % MT1;
    const int mstart = offs[e], mend = offs[e+1];
    const int m0 = mstart + mt * BM;
    if (m0 >= mend) return;
    const int mcount = min(mend - m0, BM);
    const int n0 = blockIdx.y * BN;

    __shared__ float2 ssc[NG13][BN];   // {gate_scale, up_scale} per (group, local col)
    __shared__ float  wts[BM];

    const int tid = threadIdx.x;
    const int wv = tid >> 6, lane = tid & 63;
    const int lrow = lane & 15, quad = lane >> 4;

    for (int i = tid; i < NG13 * BN; i += 256) {
        int g = i >> 6, cl = i & 63;
        size_t b = (size_t)e * NG13 * N13 + (size_t)g * N13 + n0 + cl;
        ssc[g][cl] = make_float2(w13s[b], w13s[b + I_DIM]);
    }
    for (int m = tid; m < BM; m += 256)
        wts[m] = (m < mcount) ? pw[m0 + m] : 0.f;

    // A-frag pointers: lane's own rows, 16B contiguous per frag
    const __bf16* aptr0 = xg + (size_t)(m0 + wv*32 + lrow) * H_DIM + quad*8;
    const __bf16* aptr1 = aptr0 + (size_t)16 * H_DIM;
    const size_t  wbase = (size_t)e * KP13 * N13;
    const int*    gbase = g13 + e * H_DIM + quad*8;

    int cl[4];
    #pragma unroll
    for (int j = 0; j < 4; j++) cl[j] = j*16 + lrow;   // local col per j-block

    struct Frag { bf16x8 a0, a1; int qg[4], qu[4]; i32x4 ga, gb; };
    auto loadF = [&](int kt, Frag& f) {
        int k0 = kt * BK;
        f.a0 = *reinterpret_cast<const bf16x8*>(aptr0 + k0);
        f.a1 = *reinterpret_cast<const bf16x8*>(aptr1 + k0);
        size_t rb = wbase + (size_t)((k0 >> 3) + quad) * N13 + n0;
        #pragma unroll
        for (int j = 0; j < 4; j++) {
            f.qg[j] = w13q[rb + cl[j]];
            f.qu[j] = w13q[rb + cl[j] + I_DIM];
        }
        const i32x4* gp = reinterpret_cast<const i32x4*>(gbase + k0);
        f.ga = gp[0]; f.gb = gp[1];
    };

    f32x4 accg[2][4], accu[2][4];
    #pragma unroll
    for (int i = 0; i < 2; i++)
        #pragma unroll
        for (int j = 0; j < 4; j++) { accg[i][j] = (f32x4)(0.f); accu[i][j] = (f32x4)(0.f); }

    auto computeF = [&](const Frag& f) {
        int gs[8] = {f.ga.x, f.ga.y, f.ga.z, f.ga.w, f.gb.x, f.gb.y, f.gb.z, f.gb.w};
        #pragma unroll
        for (int j = 0; j < 4; j++) {
            bf16x8 bg, bu;
            #pragma unroll
            for (int i = 0; i < 8; i++) {
                float2 sc = ssc[gs[i]][cl[j]];
                int ng = ((f.qg[j] >> (4*i)) & 15) - 8;
                int nu = ((f.qu[j] >> (4*i)) & 15) - 8;
                bg[i] = (__bf16)((float)ng * sc.x);
                bu[i] = (__bf16)((float)nu * sc.y);
            }
            accg[0][j] = __builtin_amdgcn_mfma_f32_16x16x32_bf16(f.a0, bg, accg[0][j], 0, 0, 0);
            accg[1][j] = __builtin_amdgcn_mfma_f32_16x16x32_bf16(f.a1, bg, accg[1][j], 0, 0, 0);
            accu[0][j] = __builtin_amdgcn_mfma_f32_16x16x32_bf16(f.a0, bu, accu[0][j], 0, 0, 0);
            accu[1][j] = __builtin_amdgcn_mfma_f32_16x16x32_bf16(f.a1, bu, accu[1][j], 0, 0, 0);
        }
    };

    Frag f0, f1;
    loadF(0, f0);
    __syncthreads();                 // ssc/wts visible; the only barrier
    for (int kt = 0; kt < NT1; kt += 2) {
        loadF(kt+1, f1);             // prefetch while computing f0
        computeF(f0);
        if (kt+2 < NT1) loadF(kt+2, f0);
        computeF(f1);
    }

    // epilogue: silu(g)*u * routing weight -> bf16 act
    #pragma unroll
    for (int i = 0; i < 2; i++)
        #pragma unroll
        for (int j = 0; j < 4; j++)
            #pragma unroll
            for (int r = 0; r < 4; r++) {
                int row = wv*32 + i*16 + quad*4 + r;
                if (row < mcount) {
                    float g = accg[i][j][r];
                    float u = accu[i][j][r];
                    float a = (g / (1.f + __expf(-g))) * u * wts[row];
                    act[(size_t)(m0 + row) * I_DIM + n0 + j*16 + lrow] = (__bf16)a;
                }
            }
}

// =====================================================================
// GEMM2: out[tok,h] += act @ dequant(W2), split-K, barrier-free, atomics
// =====================================================================
__global__ __launch_bounds__(256) void k_gemm2(
    const __bf16* __restrict__ act,
    const int*    __restrict__ w2q,
    const float*  __restrict__ w2s,
    const int*    __restrict__ g2,
    const int*    __restrict__ offs,
    const int*    __restrict__ plist,
    float*        __restrict__ out) {

    const int e  = blockIdx.x / MT1;
    const int mt = blockIdx.x % MT1;
    const int mstart = offs[e], mend = offs[e+1];
    const int m0 = mstart + mt * BM;
    if (m0 >= mend) return;
    const int mcount = min(mend - m0, BM);
    const int n0 = blockIdx.y * BN;
    const int kz = blockIdx.z * KLEN2;

    __shared__ float s2[NG2][BN];
    __shared__ int   toks[BM];

    const int tid = threadIdx.x;
    const int wv = tid >> 6, lane = tid & 63;
    const int lrow = lane & 15, quad = lane >> 4;

    for (int i = tid; i < NG2 * BN; i += 256) {
        int g = i >> 6, clc = i & 63;
        s2[g][clc] = w2s[(size_t)e * NG2 * N2 + (size_t)g * N2 + n0 + clc];
    }
    for (int m = tid; m < BM; m += 256)
        toks[m] = (m < mcount) ? plist[m0 + m] : 0;

    const __bf16* aptr0 = act + (size_t)(m0 + wv*32 + lrow) * I_DIM + kz + quad*8;
    const __bf16* aptr1 = aptr0 + (size_t)16 * I_DIM;
    const size_t  wbase = (size_t)e * KP2 * N2;
    const int*    gbase = g2 + e * I_DIM + kz + quad*8;

    int cl[4];
    #pragma unroll
    for (int j = 0; j < 4; j++) cl[j] = j*16 + lrow;

    struct Frag { bf16x8 a0, a1; int q[4]; i32x4 ga, gb; };
    auto loadF = [&](int kt, Frag& f) {
        int k0 = kt * BK;
        f.a0 = *reinterpret_cast<const bf16x8*>(aptr0 + k0);
        f.a1 = *reinterpret_cast<const bf16x8*>(aptr1 + k0);
        size_t rb = wbase + (size_t)(((kz + k0) >> 3) + quad) * N2 + n0;
        #pragma unroll
        for (int j = 0; j < 4; j++) f.q[j] = w2q[rb + cl[j]];
        const i32x4* gp = reinterpret_cast<const i32x4*>(gbase + k0);
        f.ga = gp[0]; f.gb = gp[1];
    };

    f32x4 acc[2][4];
    #pragma unroll
    for (int i = 0; i < 2; i++)
        #pragma unroll
        for (int j = 0; j < 4; j++) acc[i][j] = (f32x4)(0.f);

    auto computeF = [&](const Frag& f) {
        int gs[8] = {f.ga.x, f.ga.y, f.ga.z, f.ga.w, f.gb.x, f.gb.y, f.gb.z, f.gb.w};
        #pragma unroll
        for (int j = 0; j < 4; j++) {
            bf16x8 b;
            #pragma unroll
            for (int i = 0; i < 8; i++) {
                float sc = s2[gs[i]][cl[j]];
                int nb = ((f.q[j] >> (4*i)) & 15) - 8;
                b[i] = (__bf16)((float)nb * sc);
            }
            acc[0][j] = __builtin_amdgcn_mfma_f32_16x16x32_bf16(f.a0, b, acc[0][j], 0, 0, 0);
            acc[1][j] = __builtin_amdgcn_mfma_f32_16x16x32_bf16(f.a1, b, acc[1][j], 0, 0, 0);
        }
    };

    Frag f0, f1;
    loadF(0, f0);
    __syncthreads();                 // s2/toks visible; the only barrier
    for (int kt = 0; kt < NT2; kt += 2) {
        loadF(kt+1, f1);
        computeF(f0);
        if (kt+2 < NT2) loadF(kt+2, f0);
        computeF(f1);
    }

    #pragma unroll
    for (int i = 0; i < 2; i++)
        #pragma unroll
        for (int j = 0; j < 4; j++)
            #pragma unroll
            for (int r = 0; r < 4; r++) {
                int row = wv*32 + i*16 + quad*4 + r;
                if (row < mcount)
                    atomicAdd(&out[(size_t)toks[row] * H_DIM + n0 + j*16 + lrow],
                              acc[i][j][r]);
            }
}

// =====================================================================
extern "C" void kernel_launch(void* const* d_in, const int* in_sizes, int n_in,
                              void* d_out, int out_size, void* d_ws, size_t ws_size,
                              hipStream_t stream) {
    const float* x      = (const float*)d_in[0];
    const float* logits = (const float*)d_in[1];
    const int*   w13q   = (const int*)  d_in[2];
    const int*   w2q    = (const int*)  d_in[3];
    const float* w13s   = (const float*)d_in[4];
    const float* w2s    = (const float*)d_in[5];
    const int*   g13    = (const int*)  d_in[6];
    const int*   g2     = (const int*)  d_in[7];

    char* ws = (char*)d_ws;
    int*    counts = (int*)   (ws + WS_COUNTS);
    int*    offs   = (int*)   (ws + WS_OFFS);
    int*    curs   = (int*)   (ws + WS_CURS);
    int*    tok_e  = (int*)   (ws + WS_TOKE);
    float*  tok_w  = (float*) (ws + WS_TOKW);
    int*    plist  = (int*)   (ws + WS_PLIST);
    float*  pw     = (float*) (ws + WS_PW);
    __bf16* xg     = (__bf16*)(ws + WS_XG);
    __bf16* act    = (__bf16*)(ws + WS_ACT);
    float*  out    = (float*) d_out;

    hipMemsetAsync(d_out, 0, (size_t)out_size * sizeof(float), stream);
    hipMemsetAsync(d_ws, 0, 256, stream);

    k_route  <<<T_TOK/256, 256, 0, stream>>>(logits, counts, tok_e, tok_w);
    k_scan   <<<1, 64, 0, stream>>>(counts, offs, curs);
    k_scatter<<<T_TOK/256, 256, 0, stream>>>(tok_e, tok_w, curs, plist, pw);
    k_gather <<<2*T_TOK, 128, 0, stream>>>(x, plist, xg);

    k_gemm1<<<dim3(NEXP*MT1, I_DIM/BN), 256, 0, stream>>>(
        xg, w13q, w13s, g13, offs, pw, act);
    k_gemm2<<<dim3(NEXP*MT1, N2/BN, KSPLIT2), 256, 0, stream>>>(
        act, w2q, w2s, g2, offs, plist, out);
}

// Round 5
// 603.839 us; speedup vs baseline: 2.2962x; 2.2962x over previous
//
#include <hip/hip_runtime.h>

// ---------------- problem constants ----------------
#define T_TOK 2048
#define NEXP  8
#define H_DIM 1024
#define I_DIM 4096

#define KP13 (H_DIM/8)
#define N13  (2*I_DIM)     // 8192
#define KP2  (I_DIM/8)
#define N2   (H_DIM)
#define NG13 8
#define NG2  32

#define MTE  8             // m-tiles per expert (128 rows each; covers <=1024 pairs/expert)
#define KSPLIT2 4
#define KLEN2 (I_DIM/KSPLIT2)   // 1024

typedef __bf16 bf16x8 __attribute__((ext_vector_type(8)));
typedef float  f32x4  __attribute__((ext_vector_type(4)));

#define GLD_LDS(g, l) \
  __builtin_amdgcn_global_load_lds((const __attribute__((address_space(1))) void*)(g), \
                                   (__attribute__((address_space(3))) void*)(l), 16, 0, 0)

// ---------------- workspace layout (bytes) ----------------
#define WS_COUNTS 0
#define WS_OFFS   64
#define WS_CURS   128
#define WS_TOKE   256
#define WS_TOKW   (WS_TOKE  + 2*T_TOK*4)
#define WS_PLIST  (WS_TOKW  + 2*T_TOK*4)
#define WS_PW     (WS_PLIST + 2*T_TOK*4)
#define PAIR_PAD  (2*T_TOK + 128)
#define WS_XG     131072
#define WS_ACT    (WS_XG  + PAIR_PAD*H_DIM*2)            // 4224*1024*2
#define WS_B1T    (WS_ACT + (size_t)PAIR_PAD*I_DIM*2)    // 4224*4096*2
#define WS_W2T    (WS_B1T + (size_t)NEXP*N13*H_DIM*2)    // 8*8192*1024*2
// W2T: 8*1024*4096*2 ; total ~235 MB

// =====================================================================
// Routing
// =====================================================================
__global__ void k_route(const float* __restrict__ logits,
                        int* __restrict__ counts,
                        int* __restrict__ tok_e, float* __restrict__ tok_w) {
    int t = blockIdx.x * blockDim.x + threadIdx.x;
    if (t >= T_TOK) return;
    float l[NEXP];
    #pragma unroll
    for (int e = 0; e < NEXP; e++) l[e] = logits[t * NEXP + e];
    int i0 = 0; float b0 = l[0];
    #pragma unroll
    for (int e = 1; e < NEXP; e++) if (l[e] > b0) { b0 = l[e]; i0 = e; }
    int i1 = -1; float b1 = -1e30f;
    #pragma unroll
    for (int e = 0; e < NEXP; e++) if (e != i0 && l[e] > b1) { b1 = l[e]; i1 = e; }
    float w1 = 1.f / (1.f + __expf(b0 - b1));
    float w0 = 1.f - w1;
    tok_e[2*t] = i0; tok_e[2*t+1] = i1;
    tok_w[2*t] = w0; tok_w[2*t+1] = w1;
    atomicAdd(&counts[i0], 1);
    atomicAdd(&counts[i1], 1);
}

__global__ void k_scan(const int* __restrict__ counts,
                       int* __restrict__ offs, int* __restrict__ curs) {
    if (threadIdx.x == 0) {
        int s = 0;
        for (int e = 0; e < NEXP; e++) { offs[e] = s; curs[e] = s; s += counts[e]; }
        offs[NEXP] = s;
    }
}

__global__ void k_scatter(const int* __restrict__ tok_e, const float* __restrict__ tok_w,
                          int* __restrict__ curs,
                          int* __restrict__ plist, float* __restrict__ pw) {
    int t = blockIdx.x * blockDim.x + threadIdx.x;
    if (t >= T_TOK) return;
    #pragma unroll
    for (int s = 0; s < 2; s++) {
        int e = tok_e[2*t+s];
        int pos = atomicAdd(&curs[e], 1);
        plist[pos] = t;
        pw[pos] = tok_w[2*t+s];
    }
}

// gather x rows in pair order, fp32 -> bf16
__global__ void k_gather(const float* __restrict__ x, const int* __restrict__ plist,
                         __bf16* __restrict__ xg) {
    int p = blockIdx.x;
    int t = plist[p];
    int i = threadIdx.x;
    const f32x4* src = reinterpret_cast<const f32x4*>(x + (size_t)t * H_DIM);
    f32x4 v0 = src[i*2], v1 = src[i*2+1];
    __align__(16) __bf16 tb[8];
    #pragma unroll
    for (int j = 0; j < 4; j++) { tb[j] = (__bf16)v0[j]; tb[4+j] = (__bf16)v1[j]; }
    *reinterpret_cast<f32x4*>(xg + (size_t)p * H_DIM + i*8) = *reinterpret_cast<f32x4*>(tb);
}

// =====================================================================
// Transpose-dequant: int4 [K/8][N] -> bf16 B^T [R][K]  (R rows map to src cols)
// INTERLEAVE (w13): row r -> src col ((r>>4)<<3)+(r&7) + ((r>>3)&1)*N/2
//   => 16-row groups: rows 0-7 = gate cols 8g..8g+7, rows 8-15 = up same cols
// =====================================================================
template<bool INTERLEAVE>
__global__ __launch_bounds__(256) void k_dequant(
    const int* __restrict__ q, const float* __restrict__ s, const int* __restrict__ g,
    __bf16* __restrict__ outw, int R, int K, int N, int NG) {

    const int e  = blockIdx.z;
    const int r0 = blockIdx.x * 64;
    const int k0 = blockIdx.y * 128;
    const int*   qe = q + (size_t)e * (K/8) * N;
    const float* se = s + (size_t)e * NG * N;
    const int*   ge = g + (size_t)e * K + k0;
    __bf16*      oe = outw + (size_t)e * R * K;

    __shared__ __align__(16) __bf16 tile[64][128];

    const int t  = threadIdx.x;
    const int rl = t & 63, kq = t >> 6;
    const int r  = r0 + rl;
    const int S  = INTERLEAVE ? (((r >> 4) << 3) + (r & 7) + (((r >> 3) & 1) ? (N >> 1) : 0))
                              : r;
    #pragma unroll
    for (int jj = 0; jj < 4; jj++) {
        int kp = kq + jj*4;                       // 0..15
        int qv = qe[(size_t)(k0/8 + kp) * N + S];
        __align__(16) __bf16 tmp[8];
        #pragma unroll
        for (int j2 = 0; j2 < 8; j2++) {
            float sc = se[(size_t)ge[kp*8 + j2] * N + S];
            tmp[j2] = (__bf16)((float)(((qv >> (4*j2)) & 15) - 8) * sc);
        }
        int c = kp ^ (rl & 15);
        *reinterpret_cast<f32x4*>(&tile[rl][c*8]) = *reinterpret_cast<f32x4*>(tmp);
    }
    __syncthreads();
    #pragma unroll
    for (int i = 0; i < 4; i++) {
        int sidx = t + i*256;                     // 0..1023
        int row = sidx >> 4, ch = sidx & 15;
        int cs = ch ^ (row & 15);
        *reinterpret_cast<f32x4*>(oe + (size_t)(r0+row)*K + k0 + ch*8)
            = *reinterpret_cast<const f32x4*>(&tile[row][cs*8]);
    }
}

// =====================================================================
// m97-style GEMM core: 128x128 tile, BK=32, single-buffer LDS,
// issue-DMA -> barrier -> ds_read_b128 + 16 MFMA per wave-tile.
// =====================================================================
__global__ __launch_bounds__(256) void k_gemm1(
    const __bf16* __restrict__ xg,
    const __bf16* __restrict__ B1t,
    const int*    __restrict__ offs,
    const float*  __restrict__ pw,
    __bf16*       __restrict__ act) {

    const int e  = blockIdx.x >> 3;
    const int mt = blockIdx.x & (MTE-1);
    const int mstart = offs[e], mend = offs[e+1];
    const int m0 = mstart + mt * 128;
    if (m0 >= mend) return;
    const int mcount = min(mend - m0, 128);
    const int n0r = blockIdx.y * 128;             // B1t row base

    __shared__ __align__(16) __bf16 As[128*32];
    __shared__ __align__(16) __bf16 Bs[128*32];
    __shared__ float wts[128];

    const int tid = threadIdx.x;
    const int wv = tid >> 6, lane = tid & 63;
    const int lrow = lane & 15, quad = lane >> 4;
    const int wr = (wv >> 1) * 64, wc = (wv & 1) * 64;

    for (int m = tid; m < 128; m += 256)
        wts[m] = (m < mcount) ? pw[m0 + m] : 0.f;

    const __bf16* Abase = xg  + (size_t)m0 * H_DIM;
    const __bf16* Bbase = B1t + ((size_t)e * N13 + n0r) * H_DIM;

    f32x4 acc[4][4];
    #pragma unroll
    for (int i = 0; i < 4; i++)
        #pragma unroll
        for (int j = 0; j < 4; j++) acc[i][j] = (f32x4)(0.f);

    const int s0 = wv*64 + lane;                  // DMA slot (h=0)
    const int arow0 = s0 >> 2, ach0 = (s0 & 3)*8;
    const int arow1 = (s0+256) >> 2, ach1 = ((s0+256) & 3)*8;

    for (int kt = 0; kt < H_DIM/32; kt++) {
        const int k0 = kt * 32;
        __syncthreads();                          // prev tile consumed
        GLD_LDS(Abase + (size_t)arow0*H_DIM + k0 + ach0, As + s0*8);
        GLD_LDS(Bbase + (size_t)arow0*H_DIM + k0 + ach0, Bs + s0*8);
        GLD_LDS(Abase + (size_t)arow1*H_DIM + k0 + ach1, As + (s0+256)*8);
        GLD_LDS(Bbase + (size_t)arow1*H_DIM + k0 + ach1, Bs + (s0+256)*8);
        __syncthreads();                          // DMA drained (vmcnt0 at barrier)
        bf16x8 a[4], b[4];
        #pragma unroll
        for (int i = 0; i < 4; i++)
            a[i] = *reinterpret_cast<const bf16x8*>(&As[(wr + 16*i + lrow)*32 + quad*8]);
        #pragma unroll
        for (int j = 0; j < 4; j++)
            b[j] = *reinterpret_cast<const bf16x8*>(&Bs[(wc + 16*j + lrow)*32 + quad*8]);
        #pragma unroll
        for (int j = 0; j < 4; j++)
            #pragma unroll
            for (int i = 0; i < 4; i++)
                acc[i][j] = __builtin_amdgcn_mfma_f32_16x16x32_bf16(a[i], b[j], acc[i][j], 0, 0, 0);
    }

    // epilogue: lanes lrow<8 hold gate, lrow>=8 hold up of the same logical col
    #pragma unroll
    for (int j = 0; j < 4; j++) {
        const int c0 = ((n0r + wc + 16*j) >> 1);
        #pragma unroll
        for (int i = 0; i < 4; i++)
            #pragma unroll
            for (int rr = 0; rr < 4; rr++) {
                float v = acc[i][j][rr];
                float partner = __shfl_xor(v, 8, 64);
                int m = wr + 16*i + quad*4 + rr;
                if (lrow < 8 && m < mcount) {
                    float gg = v, uu = partner;
                    float a = (gg / (1.f + __expf(-gg))) * uu * wts[m];
                    act[(size_t)(m0 + m) * I_DIM + c0 + lrow] = (__bf16)a;
                }
            }
    }
}

__global__ __launch_bounds__(256) void k_gemm2(
    const __bf16* __restrict__ act,
    const __bf16* __restrict__ W2t,
    const int*    __restrict__ offs,
    const int*    __restrict__ plist,
    float*        __restrict__ out) {

    const int e  = blockIdx.x >> 3;
    const int mt = blockIdx.x & (MTE-1);
    const int mstart = offs[e], mend = offs[e+1];
    const int m0 = mstart + mt * 128;
    if (m0 >= mend) return;
    const int mcount = min(mend - m0, 128);
    const int n0 = blockIdx.y * 128;
    const int kz = blockIdx.z * KLEN2;

    __shared__ __align__(16) __bf16 As[128*32];
    __shared__ __align__(16) __bf16 Bs[128*32];
    __shared__ int toks[128];

    const int tid = threadIdx.x;
    const int wv = tid >> 6, lane = tid & 63;
    const int lrow = lane & 15, quad = lane >> 4;
    const int wr = (wv >> 1) * 64, wc = (wv & 1) * 64;

    for (int m = tid; m < 128; m += 256)
        toks[m] = (m < mcount) ? plist[m0 + m] : 0;

    const __bf16* Abase = act + (size_t)m0 * I_DIM + kz;
    const __bf16* Bbase = W2t + ((size_t)e * N2 + n0) * I_DIM + kz;

    f32x4 acc[4][4];
    #pragma unroll
    for (int i = 0; i < 4; i++)
        #pragma unroll
        for (int j = 0; j < 4; j++) acc[i][j] = (f32x4)(0.f);

    const int s0 = wv*64 + lane;
    const int arow0 = s0 >> 2, ach0 = (s0 & 3)*8;
    const int arow1 = (s0+256) >> 2, ach1 = ((s0+256) & 3)*8;

    for (int kt = 0; kt < KLEN2/32; kt++) {
        const int k0 = kt * 32;
        __syncthreads();
        GLD_LDS(Abase + (size_t)arow0*I_DIM + k0 + ach0, As + s0*8);
        GLD_LDS(Bbase + (size_t)arow0*I_DIM + k0 + ach0, Bs + s0*8);
        GLD_LDS(Abase + (size_t)arow1*I_DIM + k0 + ach1, As + (s0+256)*8);
        GLD_LDS(Bbase + (size_t)arow1*I_DIM + k0 + ach1, Bs + (s0+256)*8);
        __syncthreads();
        bf16x8 a[4], b[4];
        #pragma unroll
        for (int i = 0; i < 4; i++)
            a[i] = *reinterpret_cast<const bf16x8*>(&As[(wr + 16*i + lrow)*32 + quad*8]);
        #pragma unroll
        for (int j = 0; j < 4; j++)
            b[j] = *reinterpret_cast<const bf16x8*>(&Bs[(wc + 16*j + lrow)*32 + quad*8]);
        #pragma unroll
        for (int j = 0; j < 4; j++)
            #pragma unroll
            for (int i = 0; i < 4; i++)
                acc[i][j] = __builtin_amdgcn_mfma_f32_16x16x32_bf16(a[i], b[j], acc[i][j], 0, 0, 0);
    }

    #pragma unroll
    for (int j = 0; j < 4; j++) {
        int h = n0 + wc + 16*j + lrow;
        #pragma unroll
        for (int i = 0; i < 4; i++)
            #pragma unroll
            for (int rr = 0; rr < 4; rr++) {
                int m = wr + 16*i + quad*4 + rr;
                if (m < mcount)
                    atomicAdd(&out[(size_t)toks[m] * H_DIM + h], acc[i][j][rr]);
            }
    }
}

// =====================================================================
extern "C" void kernel_launch(void* const* d_in, const int* in_sizes, int n_in,
                              void* d_out, int out_size, void* d_ws, size_t ws_size,
                              hipStream_t stream) {
    const float* x      = (const float*)d_in[0];
    const float* logits = (const float*)d_in[1];
    const int*   w13q   = (const int*)  d_in[2];
    const int*   w2q    = (const int*)  d_in[3];
    const float* w13s   = (const float*)d_in[4];
    const float* w2s    = (const float*)d_in[5];
    const int*   g13    = (const int*)  d_in[6];
    const int*   g2     = (const int*)  d_in[7];

    char* ws = (char*)d_ws;
    int*    counts = (int*)   (ws + WS_COUNTS);
    int*    offs   = (int*)   (ws + WS_OFFS);
    int*    curs   = (int*)   (ws + WS_CURS);
    int*    tok_e  = (int*)   (ws + WS_TOKE);
    float*  tok_w  = (float*) (ws + WS_TOKW);
    int*    plist  = (int*)   (ws + WS_PLIST);
    float*  pw     = (float*) (ws + WS_PW);
    __bf16* xg     = (__bf16*)(ws + WS_XG);
    __bf16* act    = (__bf16*)(ws + WS_ACT);
    __bf16* B1t    = (__bf16*)(ws + WS_B1T);
    __bf16* W2t    = (__bf16*)(ws + WS_W2T);
    float*  out    = (float*) d_out;

    hipMemsetAsync(d_out, 0, (size_t)out_size * sizeof(float), stream);
    hipMemsetAsync(d_ws, 0, 256, stream);

    // weight dequant (independent of routing)
    k_dequant<true ><<<dim3(N13/64, H_DIM/128, NEXP), 256, 0, stream>>>(
        w13q, w13s, g13, B1t, N13, H_DIM, N13, NG13);
    k_dequant<false><<<dim3(N2/64,  I_DIM/128, NEXP), 256, 0, stream>>>(
        w2q,  w2s,  g2,  W2t, N2,  I_DIM, N2,  NG2);

    // routing chain
    k_route  <<<T_TOK/256, 256, 0, stream>>>(logits, counts, tok_e, tok_w);
    k_scan   <<<1, 64, 0, stream>>>(counts, offs, curs);
    k_scatter<<<T_TOK/256, 256, 0, stream>>>(tok_e, tok_w, curs, plist, pw);
    k_gather <<<2*T_TOK, 128, 0, stream>>>(x, plist, xg);

    // GEMMs
    k_gemm1<<<dim3(NEXP*MTE, N13/128), 256, 0, stream>>>(xg, B1t, offs, pw, act);
    k_gemm2<<<dim3(NEXP*MTE, N2/128, KSPLIT2), 256, 0, stream>>>(act, W2t, offs, plist, out);
}

// Round 6
// 582.370 us; speedup vs baseline: 2.3808x; 1.0369x over previous
//
#include <hip/hip_runtime.h>

// ---------------- problem constants ----------------
#define T_TOK 2048
#define NEXP  8
#define H_DIM 1024
#define I_DIM 4096

#define KP13 (H_DIM/8)
#define N13  (2*I_DIM)     // 8192
#define KP2  (I_DIM/8)
#define N2   (H_DIM)
#define NG13 8
#define NG2  32

#define MTE  8             // m-tiles per expert (128 rows each)
#define KSPLIT2 4
#define KLEN2 (I_DIM/KSPLIT2)   // 1024
#define BK   64

typedef __bf16 bf16x8 __attribute__((ext_vector_type(8)));
typedef float  f32x4  __attribute__((ext_vector_type(4)));

#define GLD_LDS(g, l) \
  __builtin_amdgcn_global_load_lds((const __attribute__((address_space(1))) void*)(g), \
                                   (__attribute__((address_space(3))) void*)(l), 16, 0, 0)

// ---------------- workspace layout (bytes) ----------------
#define WS_COUNTS 0
#define WS_OFFS   64
#define WS_CURS   128
#define WS_TOKE   256
#define WS_TOKW   (WS_TOKE  + 2*T_TOK*4)
#define WS_PLIST  (WS_TOKW  + 2*T_TOK*4)
#define WS_PW     (WS_PLIST + 2*T_TOK*4)
#define PAIR_PAD  (2*T_TOK + 128)
#define WS_XG     131072
#define WS_ACT    (WS_XG  + PAIR_PAD*H_DIM*2)
#define WS_B1T    (WS_ACT + (size_t)PAIR_PAD*I_DIM*2)
#define WS_W2T    (WS_B1T + (size_t)NEXP*N13*H_DIM*2)

// =====================================================================
// Routing
// =====================================================================
__global__ void k_route(const float* __restrict__ logits,
                        int* __restrict__ counts,
                        int* __restrict__ tok_e, float* __restrict__ tok_w) {
    int t = blockIdx.x * blockDim.x + threadIdx.x;
    if (t >= T_TOK) return;
    float l[NEXP];
    #pragma unroll
    for (int e = 0; e < NEXP; e++) l[e] = logits[t * NEXP + e];
    int i0 = 0; float b0 = l[0];
    #pragma unroll
    for (int e = 1; e < NEXP; e++) if (l[e] > b0) { b0 = l[e]; i0 = e; }
    int i1 = -1; float b1 = -1e30f;
    #pragma unroll
    for (int e = 0; e < NEXP; e++) if (e != i0 && l[e] > b1) { b1 = l[e]; i1 = e; }
    float w1 = 1.f / (1.f + __expf(b0 - b1));
    float w0 = 1.f - w1;
    tok_e[2*t] = i0; tok_e[2*t+1] = i1;
    tok_w[2*t] = w0; tok_w[2*t+1] = w1;
    atomicAdd(&counts[i0], 1);
    atomicAdd(&counts[i1], 1);
}

__global__ void k_scan(const int* __restrict__ counts,
                       int* __restrict__ offs, int* __restrict__ curs) {
    if (threadIdx.x == 0) {
        int s = 0;
        for (int e = 0; e < NEXP; e++) { offs[e] = s; curs[e] = s; s += counts[e]; }
        offs[NEXP] = s;
    }
}

__global__ void k_scatter(const int* __restrict__ tok_e, const float* __restrict__ tok_w,
                          int* __restrict__ curs,
                          int* __restrict__ plist, float* __restrict__ pw) {
    int t = blockIdx.x * blockDim.x + threadIdx.x;
    if (t >= T_TOK) return;
    #pragma unroll
    for (int s = 0; s < 2; s++) {
        int e = tok_e[2*t+s];
        int pos = atomicAdd(&curs[e], 1);
        plist[pos] = t;
        pw[pos] = tok_w[2*t+s];
    }
}

__global__ void k_gather(const float* __restrict__ x, const int* __restrict__ plist,
                         __bf16* __restrict__ xg) {
    int p = blockIdx.x;
    int t = plist[p];
    int i = threadIdx.x;
    const f32x4* src = reinterpret_cast<const f32x4*>(x + (size_t)t * H_DIM);
    f32x4 v0 = src[i*2], v1 = src[i*2+1];
    __align__(16) __bf16 tb[8];
    #pragma unroll
    for (int j = 0; j < 4; j++) { tb[j] = (__bf16)v0[j]; tb[4+j] = (__bf16)v1[j]; }
    *reinterpret_cast<f32x4*>(xg + (size_t)p * H_DIM + i*8) = *reinterpret_cast<f32x4*>(tb);
}

// =====================================================================
// Transpose-dequant: int4 [K/8][N] -> bf16 B^T [R][K]
// INTERLEAVE (w13): row r -> src col ((r>>4)<<3)+(r&7) + ((r>>3)&1)*N/2
// =====================================================================
template<bool INTERLEAVE>
__global__ __launch_bounds__(256) void k_dequant(
    const int* __restrict__ q, const float* __restrict__ s, const int* __restrict__ g,
    __bf16* __restrict__ outw, int R, int K, int N, int NG) {

    const int e  = blockIdx.z;
    const int r0 = blockIdx.x * 64;
    const int k0 = blockIdx.y * 128;
    const int*   qe = q + (size_t)e * (K/8) * N;
    const float* se = s + (size_t)e * NG * N;
    const int*   ge = g + (size_t)e * K + k0;
    __bf16*      oe = outw + (size_t)e * R * K;

    __shared__ __align__(16) __bf16 tile[64][128];

    const int t  = threadIdx.x;
    const int rl = t & 63, kq = t >> 6;
    const int r  = r0 + rl;
    const int S  = INTERLEAVE ? (((r >> 4) << 3) + (r & 7) + (((r >> 3) & 1) ? (N >> 1) : 0))
                              : r;
    #pragma unroll
    for (int jj = 0; jj < 4; jj++) {
        int kp = kq + jj*4;
        int qv = qe[(size_t)(k0/8 + kp) * N + S];
        __align__(16) __bf16 tmp[8];
        #pragma unroll
        for (int j2 = 0; j2 < 8; j2++) {
            float sc = se[(size_t)ge[kp*8 + j2] * N + S];
            tmp[j2] = (__bf16)((float)(((qv >> (4*j2)) & 15) - 8) * sc);
        }
        int c = kp ^ (rl & 15);
        *reinterpret_cast<f32x4*>(&tile[rl][c*8]) = *reinterpret_cast<f32x4*>(tmp);
    }
    __syncthreads();
    #pragma unroll
    for (int i = 0; i < 4; i++) {
        int sidx = t + i*256;
        int row = sidx >> 4, ch = sidx & 15;
        int cs = ch ^ (row & 15);
        *reinterpret_cast<f32x4*>(oe + (size_t)(r0+row)*K + k0 + ch*8)
            = *reinterpret_cast<const f32x4*>(&tile[row][cs*8]);
    }
}

// =====================================================================
// GEMM core: 128x128 tile, BK=64, single-buffer LDS, DMA staging with
// src-side XOR swizzle (slot (row,c) holds data chunk c^(row&7) -> 2-way
// conflict-free ds_read_b128 at row stride 64 bf16).
// =====================================================================
__global__ __launch_bounds__(256) void k_gemm1(
    const __bf16* __restrict__ xg,
    const __bf16* __restrict__ B1t,
    const int*    __restrict__ offs,
    const float*  __restrict__ pw,
    __bf16*       __restrict__ act) {

    const int e  = blockIdx.x >> 3;
    const int mt = blockIdx.x & (MTE-1);
    const int mstart = offs[e], mend = offs[e+1];
    const int m0 = mstart + mt * 128;
    if (m0 >= mend) return;
    const int mcount = min(mend - m0, 128);
    const int n0r = blockIdx.y * 128;

    __shared__ __align__(16) __bf16 As[128*BK];
    __shared__ __align__(16) __bf16 Bs[128*BK];
    __shared__ float wts[128];

    const int tid = threadIdx.x;
    const int wv = tid >> 6, lane = tid & 63;
    const int lrow = lane & 15, quad = lane >> 4;
    const int wr = (wv >> 1) * 64, wc = (wv & 1) * 64;

    for (int m = tid; m < 128; m += 256)
        wts[m] = (m < mcount) ? pw[m0 + m] : 0.f;

    const __bf16* Abase = xg  + (size_t)m0 * H_DIM;
    const __bf16* Bbase = B1t + ((size_t)e * N13 + n0r) * H_DIM;

    f32x4 acc[4][4];
    #pragma unroll
    for (int i = 0; i < 4; i++)
        #pragma unroll
        for (int j = 0; j < 4; j++) acc[i][j] = (f32x4)(0.f);

    // DMA slot geometry: slot s (0..1023): row=s>>3, c=s&7, src chunk c^(row&7)
    int srow[4], soff[4];
    #pragma unroll
    for (int qq = 0; qq < 4; qq++) {
        int s = tid + qq*256;
        int row = s >> 3, c = s & 7;
        srow[qq] = row;
        soff[qq] = ((c ^ (row & 7)) * 8);
    }
    const int sw = lrow & 7;   // frag-read swizzle (row&7 == lrow&7 here)

    for (int kt = 0; kt < H_DIM/BK; kt++) {
        const int k0 = kt * BK;
        __syncthreads();                          // prev tile consumed
        #pragma unroll
        for (int qq = 0; qq < 4; qq++) {
            int s = tid + qq*256;
            GLD_LDS(Abase + (size_t)srow[qq]*H_DIM + k0 + soff[qq], As + s*8);
            GLD_LDS(Bbase + (size_t)srow[qq]*H_DIM + k0 + soff[qq], Bs + s*8);
        }
        __syncthreads();                          // DMA drained
        #pragma unroll
        for (int h = 0; h < 2; h++) {
            const int co = (((h << 2) | quad) ^ sw) * 8;
            bf16x8 a[4], b[4];
            #pragma unroll
            for (int i = 0; i < 4; i++)
                a[i] = *reinterpret_cast<const bf16x8*>(&As[(wr + 16*i + lrow)*BK + co]);
            #pragma unroll
            for (int j = 0; j < 4; j++)
                b[j] = *reinterpret_cast<const bf16x8*>(&Bs[(wc + 16*j + lrow)*BK + co]);
            #pragma unroll
            for (int j = 0; j < 4; j++)
                #pragma unroll
                for (int i = 0; i < 4; i++)
                    acc[i][j] = __builtin_amdgcn_mfma_f32_16x16x32_bf16(a[i], b[j], acc[i][j], 0, 0, 0);
        }
    }

    // epilogue: lrow<8 = gate, lrow>=8 = up of same logical col (shfl pair)
    #pragma unroll
    for (int j = 0; j < 4; j++) {
        const int c0 = ((n0r + wc + 16*j) >> 1);
        #pragma unroll
        for (int i = 0; i < 4; i++)
            #pragma unroll
            for (int rr = 0; rr < 4; rr++) {
                float v = acc[i][j][rr];
                float partner = __shfl_xor(v, 8, 64);
                int m = wr + 16*i + quad*4 + rr;
                if (lrow < 8 && m < mcount) {
                    float gg = v, uu = partner;
                    float a = (gg / (1.f + __expf(-gg))) * uu * wts[m];
                    act[(size_t)(m0 + m) * I_DIM + c0 + lrow] = (__bf16)a;
                }
            }
    }
}

__global__ __launch_bounds__(256) void k_gemm2(
    const __bf16* __restrict__ act,
    const __bf16* __restrict__ W2t,
    const int*    __restrict__ offs,
    const int*    __restrict__ plist,
    float*        __restrict__ out) {

    const int e  = blockIdx.x >> 3;
    const int mt = blockIdx.x & (MTE-1);
    const int mstart = offs[e], mend = offs[e+1];
    const int m0 = mstart + mt * 128;
    if (m0 >= mend) return;
    const int mcount = min(mend - m0, 128);
    const int n0 = blockIdx.y * 128;
    const int kz = blockIdx.z * KLEN2;

    __shared__ __align__(16) __bf16 As[128*BK];
    __shared__ __align__(16) __bf16 Bs[128*BK];
    __shared__ int toks[128];

    const int tid = threadIdx.x;
    const int wv = tid >> 6, lane = tid & 63;
    const int lrow = lane & 15, quad = lane >> 4;
    const int wr = (wv >> 1) * 64, wc = (wv & 1) * 64;

    for (int m = tid; m < 128; m += 256)
        toks[m] = (m < mcount) ? plist[m0 + m] : 0;

    const __bf16* Abase = act + (size_t)m0 * I_DIM + kz;
    const __bf16* Bbase = W2t + ((size_t)e * N2 + n0) * I_DIM + kz;

    f32x4 acc[4][4];
    #pragma unroll
    for (int i = 0; i < 4; i++)
        #pragma unroll
        for (int j = 0; j < 4; j++) acc[i][j] = (f32x4)(0.f);

    int srow[4], soff[4];
    #pragma unroll
    for (int qq = 0; qq < 4; qq++) {
        int s = tid + qq*256;
        int row = s >> 3, c = s & 7;
        srow[qq] = row;
        soff[qq] = ((c ^ (row & 7)) * 8);
    }
    const int sw = lrow & 7;

    for (int kt = 0; kt < KLEN2/BK; kt++) {
        const int k0 = kt * BK;
        __syncthreads();
        #pragma unroll
        for (int qq = 0; qq < 4; qq++) {
            int s = tid + qq*256;
            GLD_LDS(Abase + (size_t)srow[qq]*I_DIM + k0 + soff[qq], As + s*8);
            GLD_LDS(Bbase + (size_t)srow[qq]*I_DIM + k0 + soff[qq], Bs + s*8);
        }
        __syncthreads();
        #pragma unroll
        for (int h = 0; h < 2; h++) {
            const int co = (((h << 2) | quad) ^ sw) * 8;
            bf16x8 a[4], b[4];
            #pragma unroll
            for (int i = 0; i < 4; i++)
                a[i] = *reinterpret_cast<const bf16x8*>(&As[(wr + 16*i + lrow)*BK + co]);
            #pragma unroll
            for (int j = 0; j < 4; j++)
                b[j] = *reinterpret_cast<const bf16x8*>(&Bs[(wc + 16*j + lrow)*BK + co]);
            #pragma unroll
            for (int j = 0; j < 4; j++)
                #pragma unroll
                for (int i = 0; i < 4; i++)
                    acc[i][j] = __builtin_amdgcn_mfma_f32_16x16x32_bf16(a[i], b[j], acc[i][j], 0, 0, 0);
        }
    }

    #pragma unroll
    for (int j = 0; j < 4; j++) {
        int h = n0 + wc + 16*j + lrow;
        #pragma unroll
        for (int i = 0; i < 4; i++)
            #pragma unroll
            for (int rr = 0; rr < 4; rr++) {
                int m = wr + 16*i + quad*4 + rr;
                if (m < mcount)
                    atomicAdd(&out[(size_t)toks[m] * H_DIM + h], acc[i][j][rr]);
            }
    }
}

// =====================================================================
extern "C" void kernel_launch(void* const* d_in, const int* in_sizes, int n_in,
                              void* d_out, int out_size, void* d_ws, size_t ws_size,
                              hipStream_t stream) {
    const float* x      = (const float*)d_in[0];
    const float* logits = (const float*)d_in[1];
    const int*   w13q   = (const int*)  d_in[2];
    const int*   w2q    = (const int*)  d_in[3];
    const float* w13s   = (const float*)d_in[4];
    const float* w2s    = (const float*)d_in[5];
    const int*   g13    = (const int*)  d_in[6];
    const int*   g2     = (const int*)  d_in[7];

    char* ws = (char*)d_ws;
    int*    counts = (int*)   (ws + WS_COUNTS);
    int*    offs   = (int*)   (ws + WS_OFFS);
    int*    curs   = (int*)   (ws + WS_CURS);
    int*    tok_e  = (int*)   (ws + WS_TOKE);
    float*  tok_w  = (float*) (ws + WS_TOKW);
    int*    plist  = (int*)   (ws + WS_PLIST);
    float*  pw     = (float*) (ws + WS_PW);
    __bf16* xg     = (__bf16*)(ws + WS_XG);
    __bf16* act    = (__bf16*)(ws + WS_ACT);
    __bf16* B1t    = (__bf16*)(ws + WS_B1T);
    __bf16* W2t    = (__bf16*)(ws + WS_W2T);
    float*  out    = (float*) d_out;

    hipMemsetAsync(d_out, 0, (size_t)out_size * sizeof(float), stream);
    hipMemsetAsync(d_ws, 0, 256, stream);

    k_dequant<true ><<<dim3(N13/64, H_DIM/128, NEXP), 256, 0, stream>>>(
        w13q, w13s, g13, B1t, N13, H_DIM, N13, NG13);
    k_dequant<false><<<dim3(N2/64,  I_DIM/128, NEXP), 256, 0, stream>>>(
        w2q,  w2s,  g2,  W2t, N2,  I_DIM, N2,  NG2);

    k_route  <<<T_TOK/256, 256, 0, stream>>>(logits, counts, tok_e, tok_w);
    k_scan   <<<1, 64, 0, stream>>>(counts, offs, curs);
    k_scatter<<<T_TOK/256, 256, 0, stream>>>(tok_e, tok_w, curs, plist, pw);
    k_gather <<<2*T_TOK, 128, 0, stream>>>(x, plist, xg);

    k_gemm1<<<dim3(NEXP*MTE, N13/128), 256, 0, stream>>>(xg, B1t, offs, pw, act);
    k_gemm2<<<dim3(NEXP*MTE, N2/128, KSPLIT2), 256, 0, stream>>>(act, W2t, offs, plist, out);
}

// Round 7
// 559.554 us; speedup vs baseline: 2.4779x; 1.0408x over previous
//
#include <hip/hip_runtime.h>

// ---------------- problem constants ----------------
#define T_TOK 2048
#define NEXP  8
#define H_DIM 1024
#define I_DIM 4096

#define KP13 (H_DIM/8)
#define N13  (2*I_DIM)     // 8192
#define KP2  (I_DIM/8)
#define N2   (H_DIM)
#define NG13 8
#define NG2  32

#define MTE  8             // m-tiles per expert (128 rows each)
#define KSPLIT2 4
#define KLEN2 (I_DIM/KSPLIT2)   // 1024
#define BK   64

typedef __bf16 bf16x8 __attribute__((ext_vector_type(8)));
typedef float  f32x4  __attribute__((ext_vector_type(4)));

#define GLD_LDS(g, l) \
  __builtin_amdgcn_global_load_lds((const __attribute__((address_space(1))) void*)(g), \
                                   (__attribute__((address_space(3))) void*)(l), 16, 0, 0)

// ---------------- workspace layout (bytes) ----------------
#define WS_COUNTS 0
#define WS_OFFS   64
#define WS_CURS   128
#define WS_TOKE   256
#define WS_TOKW   (WS_TOKE  + 2*T_TOK*4)
#define WS_PLIST  (WS_TOKW  + 2*T_TOK*4)
#define WS_PW     (WS_PLIST + 2*T_TOK*4)
#define PAIR_PAD  (2*T_TOK + 128)
#define WS_XG     131072
#define WS_ACT    (WS_XG  + PAIR_PAD*H_DIM*2)
#define WS_B1T    (WS_ACT + (size_t)PAIR_PAD*I_DIM*2)
#define WS_W2T    (WS_B1T + (size_t)NEXP*N13*H_DIM*2)

// =====================================================================
// Routing
// =====================================================================
__global__ void k_route(const float* __restrict__ logits,
                        int* __restrict__ counts,
                        int* __restrict__ tok_e, float* __restrict__ tok_w) {
    int t = blockIdx.x * blockDim.x + threadIdx.x;
    if (t >= T_TOK) return;
    float l[NEXP];
    #pragma unroll
    for (int e = 0; e < NEXP; e++) l[e] = logits[t * NEXP + e];
    int i0 = 0; float b0 = l[0];
    #pragma unroll
    for (int e = 1; e < NEXP; e++) if (l[e] > b0) { b0 = l[e]; i0 = e; }
    int i1 = -1; float b1 = -1e30f;
    #pragma unroll
    for (int e = 0; e < NEXP; e++) if (e != i0 && l[e] > b1) { b1 = l[e]; i1 = e; }
    float w1 = 1.f / (1.f + __expf(b0 - b1));
    float w0 = 1.f - w1;
    tok_e[2*t] = i0; tok_e[2*t+1] = i1;
    tok_w[2*t] = w0; tok_w[2*t+1] = w1;
    atomicAdd(&counts[i0], 1);
    atomicAdd(&counts[i1], 1);
}

__global__ void k_scan(const int* __restrict__ counts,
                       int* __restrict__ offs, int* __restrict__ curs) {
    if (threadIdx.x == 0) {
        int s = 0;
        for (int e = 0; e < NEXP; e++) { offs[e] = s; curs[e] = s; s += counts[e]; }
        offs[NEXP] = s;
    }
}

__global__ void k_scatter(const int* __restrict__ tok_e, const float* __restrict__ tok_w,
                          int* __restrict__ curs,
                          int* __restrict__ plist, float* __restrict__ pw) {
    int t = blockIdx.x * blockDim.x + threadIdx.x;
    if (t >= T_TOK) return;
    #pragma unroll
    for (int s = 0; s < 2; s++) {
        int e = tok_e[2*t+s];
        int pos = atomicAdd(&curs[e], 1);
        plist[pos] = t;
        pw[pos] = tok_w[2*t+s];
    }
}

__global__ void k_gather(const float* __restrict__ x, const int* __restrict__ plist,
                         __bf16* __restrict__ xg) {
    int p = blockIdx.x;
    int t = plist[p];
    int i = threadIdx.x;
    const f32x4* src = reinterpret_cast<const f32x4*>(x + (size_t)t * H_DIM);
    f32x4 v0 = src[i*2], v1 = src[i*2+1];
    __align__(16) __bf16 tb[8];
    #pragma unroll
    for (int j = 0; j < 4; j++) { tb[j] = (__bf16)v0[j]; tb[4+j] = (__bf16)v1[j]; }
    *reinterpret_cast<f32x4*>(xg + (size_t)p * H_DIM + i*8) = *reinterpret_cast<f32x4*>(tb);
}

// =====================================================================
// Transpose-dequant: int4 [K/8][N] -> bf16 B^T [R][K]
// INTERLEAVE (w13): row r -> src col ((r>>4)<<3)+(r&7) + ((r>>3)&1)*N/2
// =====================================================================
template<bool INTERLEAVE>
__global__ __launch_bounds__(256) void k_dequant(
    const int* __restrict__ q, const float* __restrict__ s, const int* __restrict__ g,
    __bf16* __restrict__ outw, int R, int K, int N, int NG) {

    const int e  = blockIdx.z;
    const int r0 = blockIdx.x * 64;
    const int k0 = blockIdx.y * 128;
    const int*   qe = q + (size_t)e * (K/8) * N;
    const float* se = s + (size_t)e * NG * N;
    const int*   ge = g + (size_t)e * K + k0;
    __bf16*      oe = outw + (size_t)e * R * K;

    __shared__ __align__(16) __bf16 tile[64][128];

    const int t  = threadIdx.x;
    const int rl = t & 63, kq = t >> 6;
    const int r  = r0 + rl;
    const int S  = INTERLEAVE ? (((r >> 4) << 3) + (r & 7) + (((r >> 3) & 1) ? (N >> 1) : 0))
                              : r;
    #pragma unroll
    for (int jj = 0; jj < 4; jj++) {
        int kp = kq + jj*4;
        int qv = qe[(size_t)(k0/8 + kp) * N + S];
        __align__(16) __bf16 tmp[8];
        #pragma unroll
        for (int j2 = 0; j2 < 8; j2++) {
            float sc = se[(size_t)ge[kp*8 + j2] * N + S];
            tmp[j2] = (__bf16)((float)(((qv >> (4*j2)) & 15) - 8) * sc);
        }
        int c = kp ^ (rl & 15);
        *reinterpret_cast<f32x4*>(&tile[rl][c*8]) = *reinterpret_cast<f32x4*>(tmp);
    }
    __syncthreads();
    #pragma unroll
    for (int i = 0; i < 4; i++) {
        int sidx = t + i*256;
        int row = sidx >> 4, ch = sidx & 15;
        int cs = ch ^ (row & 15);
        *reinterpret_cast<f32x4*>(oe + (size_t)(r0+row)*K + k0 + ch*8)
            = *reinterpret_cast<const f32x4*>(&tile[row][cs*8]);
    }
}

// =====================================================================
// GEMM core: 128x128 tile, BK=64, single-buffer LDS, src-side XOR swizzle.
// Grid linearized with mt FASTEST so concurrently-dispatched blocks share
// the same B-tile (LLC/L2 temporal reuse): id = ((e*NB + n)*MTE + mt).
// =====================================================================
__global__ __launch_bounds__(256) void k_gemm1(
    const __bf16* __restrict__ xg,
    const __bf16* __restrict__ B1t,
    const int*    __restrict__ offs,
    const float*  __restrict__ pw,
    __bf16*       __restrict__ act) {

    int id = blockIdx.x;
    const int mt = id & (MTE-1); id >>= 3;
    const int nb = id & 63;      id >>= 6;
    const int e  = id;
    const int mstart = offs[e], mend = offs[e+1];
    const int m0 = mstart + mt * 128;
    if (m0 >= mend) return;
    const int mcount = min(mend - m0, 128);
    const int n0r = nb * 128;

    __shared__ __align__(16) __bf16 As[128*BK];
    __shared__ __align__(16) __bf16 Bs[128*BK];
    __shared__ float wts[128];

    const int tid = threadIdx.x;
    const int wv = tid >> 6, lane = tid & 63;
    const int lrow = lane & 15, quad = lane >> 4;
    const int wr = (wv >> 1) * 64, wc = (wv & 1) * 64;

    for (int m = tid; m < 128; m += 256)
        wts[m] = (m < mcount) ? pw[m0 + m] : 0.f;

    const __bf16* Abase = xg  + (size_t)m0 * H_DIM;
    const __bf16* Bbase = B1t + ((size_t)e * N13 + n0r) * H_DIM;

    f32x4 acc[4][4];
    #pragma unroll
    for (int i = 0; i < 4; i++)
        #pragma unroll
        for (int j = 0; j < 4; j++) acc[i][j] = (f32x4)(0.f);

    int srow[4], soff[4];
    #pragma unroll
    for (int qq = 0; qq < 4; qq++) {
        int s = tid + qq*256;
        int row = s >> 3, c = s & 7;
        srow[qq] = row;
        soff[qq] = ((c ^ (row & 7)) * 8);
    }
    const int sw = lrow & 7;

    for (int kt = 0; kt < H_DIM/BK; kt++) {
        const int k0 = kt * BK;
        __syncthreads();
        #pragma unroll
        for (int qq = 0; qq < 4; qq++) {
            int s = tid + qq*256;
            GLD_LDS(Abase + (size_t)srow[qq]*H_DIM + k0 + soff[qq], As + s*8);
            GLD_LDS(Bbase + (size_t)srow[qq]*H_DIM + k0 + soff[qq], Bs + s*8);
        }
        __syncthreads();
        #pragma unroll
        for (int h = 0; h < 2; h++) {
            const int co = (((h << 2) | quad) ^ sw) * 8;
            bf16x8 a[4], b[4];
            #pragma unroll
            for (int i = 0; i < 4; i++)
                a[i] = *reinterpret_cast<const bf16x8*>(&As[(wr + 16*i + lrow)*BK + co]);
            #pragma unroll
            for (int j = 0; j < 4; j++)
                b[j] = *reinterpret_cast<const bf16x8*>(&Bs[(wc + 16*j + lrow)*BK + co]);
            #pragma unroll
            for (int j = 0; j < 4; j++)
                #pragma unroll
                for (int i = 0; i < 4; i++)
                    acc[i][j] = __builtin_amdgcn_mfma_f32_16x16x32_bf16(a[i], b[j], acc[i][j], 0, 0, 0);
        }
    }

    // epilogue: lrow<8 = gate, lrow>=8 = up of same logical col (shfl pair)
    #pragma unroll
    for (int j = 0; j < 4; j++) {
        const int c0 = ((n0r + wc + 16*j) >> 1);
        #pragma unroll
        for (int i = 0; i < 4; i++)
            #pragma unroll
            for (int rr = 0; rr < 4; rr++) {
                float v = acc[i][j][rr];
                float partner = __shfl_xor(v, 8, 64);
                int m = wr + 16*i + quad*4 + rr;
                if (lrow < 8 && m < mcount) {
                    float gg = v, uu = partner;
                    float a = (gg / (1.f + __expf(-gg))) * uu * wts[m];
                    act[(size_t)(m0 + m) * I_DIM + c0 + lrow] = (__bf16)a;
                }
            }
    }
}

__global__ __launch_bounds__(256) void k_gemm2(
    const __bf16* __restrict__ act,
    const __bf16* __restrict__ W2t,
    const int*    __restrict__ offs,
    const int*    __restrict__ plist,
    float*        __restrict__ out) {

    int id = blockIdx.x;
    const int mt = id & (MTE-1); id >>= 3;
    const int nb = id & 7;       id >>= 3;
    const int ks = id & (KSPLIT2-1); id >>= 2;
    const int e  = id;
    const int mstart = offs[e], mend = offs[e+1];
    const int m0 = mstart + mt * 128;
    if (m0 >= mend) return;
    const int mcount = min(mend - m0, 128);
    const int n0 = nb * 128;
    const int kz = ks * KLEN2;

    __shared__ __align__(16) __bf16 As[128*BK];
    __shared__ __align__(16) __bf16 Bs[128*BK];
    __shared__ int toks[128];

    const int tid = threadIdx.x;
    const int wv = tid >> 6, lane = tid & 63;
    const int lrow = lane & 15, quad = lane >> 4;
    const int wr = (wv >> 1) * 64, wc = (wv & 1) * 64;

    for (int m = tid; m < 128; m += 256)
        toks[m] = (m < mcount) ? plist[m0 + m] : 0;

    const __bf16* Abase = act + (size_t)m0 * I_DIM + kz;
    const __bf16* Bbase = W2t + ((size_t)e * N2 + n0) * I_DIM + kz;

    f32x4 acc[4][4];
    #pragma unroll
    for (int i = 0; i < 4; i++)
        #pragma unroll
        for (int j = 0; j < 4; j++) acc[i][j] = (f32x4)(0.f);

    int srow[4], soff[4];
    #pragma unroll
    for (int qq = 0; qq < 4; qq++) {
        int s = tid + qq*256;
        int row = s >> 3, c = s & 7;
        srow[qq] = row;
        soff[qq] = ((c ^ (row & 7)) * 8);
    }
    const int sw = lrow & 7;

    for (int kt = 0; kt < KLEN2/BK; kt++) {
        const int k0 = kt * BK;
        __syncthreads();
        #pragma unroll
        for (int qq = 0; qq < 4; qq++) {
            int s = tid + qq*256;
            GLD_LDS(Abase + (size_t)srow[qq]*I_DIM + k0 + soff[qq], As + s*8);
            GLD_LDS(Bbase + (size_t)srow[qq]*I_DIM + k0 + soff[qq], Bs + s*8);
        }
        __syncthreads();
        #pragma unroll
        for (int h = 0; h < 2; h++) {
            const int co = (((h << 2) | quad) ^ sw) * 8;
            bf16x8 a[4], b[4];
            #pragma unroll
            for (int i = 0; i < 4; i++)
                a[i] = *reinterpret_cast<const bf16x8*>(&As[(wr + 16*i + lrow)*BK + co]);
            #pragma unroll
            for (int j = 0; j < 4; j++)
                b[j] = *reinterpret_cast<const bf16x8*>(&Bs[(wc + 16*j + lrow)*BK + co]);
            #pragma unroll
            for (int j = 0; j < 4; j++)
                #pragma unroll
                for (int i = 0; i < 4; i++)
                    acc[i][j] = __builtin_amdgcn_mfma_f32_16x16x32_bf16(a[i], b[j], acc[i][j], 0, 0, 0);
        }
    }

    #pragma unroll
    for (int j = 0; j < 4; j++) {
        int h = n0 + wc + 16*j + lrow;
        #pragma unroll
        for (int i = 0; i < 4; i++)
            #pragma unroll
            for (int rr = 0; rr < 4; rr++) {
                int m = wr + 16*i + quad*4 + rr;
                if (m < mcount)
                    atomicAdd(&out[(size_t)toks[m] * H_DIM + h], acc[i][j][rr]);
            }
    }
}

// =====================================================================
extern "C" void kernel_launch(void* const* d_in, const int* in_sizes, int n_in,
                              void* d_out, int out_size, void* d_ws, size_t ws_size,
                              hipStream_t stream) {
    const float* x      = (const float*)d_in[0];
    const float* logits = (const float*)d_in[1];
    const int*   w13q   = (const int*)  d_in[2];
    const int*   w2q    = (const int*)  d_in[3];
    const float* w13s   = (const float*)d_in[4];
    const float* w2s    = (const float*)d_in[5];
    const int*   g13    = (const int*)  d_in[6];
    const int*   g2     = (const int*)  d_in[7];

    char* ws = (char*)d_ws;
    int*    counts = (int*)   (ws + WS_COUNTS);
    int*    offs   = (int*)   (ws + WS_OFFS);
    int*    curs   = (int*)   (ws + WS_CURS);
    int*    tok_e  = (int*)   (ws + WS_TOKE);
    float*  tok_w  = (float*) (ws + WS_TOKW);
    int*    plist  = (int*)   (ws + WS_PLIST);
    float*  pw     = (float*) (ws + WS_PW);
    __bf16* xg     = (__bf16*)(ws + WS_XG);
    __bf16* act    = (__bf16*)(ws + WS_ACT);
    __bf16* B1t    = (__bf16*)(ws + WS_B1T);
    __bf16* W2t    = (__bf16*)(ws + WS_W2T);
    float*  out    = (float*) d_out;

    hipMemsetAsync(d_out, 0, (size_t)out_size * sizeof(float), stream);
    hipMemsetAsync(d_ws, 0, 256, stream);

    k_dequant<true ><<<dim3(N13/64, H_DIM/128, NEXP), 256, 0, stream>>>(
        w13q, w13s, g13, B1t, N13, H_DIM, N13, NG13);
    k_dequant<false><<<dim3(N2/64,  I_DIM/128, NEXP), 256, 0, stream>>>(
        w2q,  w2s,  g2,  W2t, N2,  I_DIM, N2,  NG2);

    k_route  <<<T_TOK/256, 256, 0, stream>>>(logits, counts, tok_e, tok_w);
    k_scan   <<<1, 64, 0, stream>>>(counts, offs, curs);
    k_scatter<<<T_TOK/256, 256, 0, stream>>>(tok_e, tok_w, curs, plist, pw);
    k_gather <<<2*T_TOK, 128, 0, stream>>>(x, plist, xg);

    // mt-fastest linearized grids (B-tile temporal locality)
    k_gemm1<<<NEXP * 64 * MTE, 256, 0, stream>>>(xg, B1t, offs, pw, act);
    k_gemm2<<<NEXP * KSPLIT2 * 8 * MTE, 256, 0, stream>>>(act, W2t, offs, plist, out);
}